// Round 1
// baseline (2370.095 us; speedup 1.0000x reference)
//
#include <hip/hip_runtime.h>

#define HIDDEN 128
#define N_RAYS 65536
#define NEAR_D 0.01f
#define FAR_D 10.0f
#define MAX_ITERS 32

// Transpose W2 [k][j] -> W2T [j][k] so per-output-column weights are
// contiguous (enables merged s_load_dwordx16 scalar loads in the main kernel).
__global__ void w2_transpose_kernel(const float* __restrict__ W2,
                                    float* __restrict__ W2T) {
    int idx = blockIdx.x * blockDim.x + threadIdx.x;   // 0..16383
    int j = idx >> 7;        // output column
    int k = idx & 127;       // input row
    // consecutive threads: consecutive k -> coalesced writes to W2T
    W2T[j * HIDDEN + k] = W2[k * HIDDEN + j];
}

__launch_bounds__(64, 1)
__global__ void sphere_trace_kernel(
    const float* __restrict__ origins,
    const float* __restrict__ directions,
    const float* __restrict__ W1,   // [3][128]
    const float* __restrict__ b1,   // [128]
    const float* __restrict__ W2T,  // [128][128] transposed: W2T[j][k] = W2[k][j]
    const float* __restrict__ b2,   // [128]
    const float* __restrict__ W3,   // [128]
    const float* __restrict__ b3,   // [1]
    const float* __restrict__ Wc1,  // [3][128]
    const float* __restrict__ bc1,  // [128]
    const float* __restrict__ Wc2,  // [128][3]
    const float* __restrict__ bc2,  // [3]
    float* __restrict__ out)        // [N][3]
{
    const int ray = blockIdx.x * 64 + threadIdx.x;

    float px = origins[ray * 3 + 0];
    float py = origins[ray * 3 + 1];
    float pz = origins[ray * 3 + 2];
    const float dx = directions[ray * 3 + 0];
    const float dy = directions[ray * 3 + 1];
    const float dz = directions[ray * 3 + 2];

    float dist = 0.0f;
    bool mask = false;

    float h[HIDDEN];   // register-resident activations (constant-indexed only)

    const float b3v = b3[0];

    #pragma unroll 1
    for (int it = 0; it < MAX_ITERS; ++it) {
        // ---- layer 1: h = relu(p @ W1 + b1)  (weights wave-uniform -> s_load)
        #pragma unroll
        for (int j = 0; j < HIDDEN; ++j) {
            float a = fmaf(px, W1[j],
                      fmaf(py, W1[HIDDEN + j],
                      fmaf(pz, W1[2 * HIDDEN + j], b1[j])));
            h[j] = fmaxf(a, 0.0f);
        }

        // ---- layer 2 + layer 3 fused: sdf = relu(h @ W2 + b2) @ W3 + b3
        float s = b3v;
        #pragma unroll 1
        for (int jb = 0; jb < HIDDEN; jb += 4) {
            const float* __restrict__ w = W2T + jb * HIDDEN;
            float a0 = b2[jb + 0];
            float a1 = b2[jb + 1];
            float a2 = b2[jb + 2];
            float a3 = b2[jb + 3];
            #pragma unroll
            for (int k = 0; k < HIDDEN; ++k) {
                const float hv = h[k];
                a0 = fmaf(hv, w[0 * HIDDEN + k], a0);
                a1 = fmaf(hv, w[1 * HIDDEN + k], a1);
                a2 = fmaf(hv, w[2 * HIDDEN + k], a2);
                a3 = fmaf(hv, w[3 * HIDDEN + k], a3);
            }
            s = fmaf(fmaxf(a0, 0.0f), W3[jb + 0], s);
            s = fmaf(fmaxf(a1, 0.0f), W3[jb + 1], s);
            s = fmaf(fmaxf(a2, 0.0f), W3[jb + 2], s);
            s = fmaf(fmaxf(a3, 0.0f), W3[jb + 3], s);
        }

        // ---- march update (exact reference semantics)
        if (s <= NEAR_D && dist < FAR_D) {
            // absorbing state: point/dist frozen, final_mask set
            mask = true;
            break;
        }
        dist += s;
        px += dx * s;
        py += dy * s;
        pz += dz * s;
    }
    mask = mask || (dist < FAR_D);

    // ---- color MLP (only where mask; reference writes 0 elsewhere)
    float c0 = 0.0f, c1 = 0.0f, c2 = 0.0f;
    if (mask) {
        #pragma unroll
        for (int j = 0; j < HIDDEN; ++j) {
            float a = fmaf(px, Wc1[j],
                      fmaf(py, Wc1[HIDDEN + j],
                      fmaf(pz, Wc1[2 * HIDDEN + j], bc1[j])));
            h[j] = fmaxf(a, 0.0f);
        }
        float a0 = bc2[0], a1 = bc2[1], a2 = bc2[2];
        #pragma unroll
        for (int j = 0; j < HIDDEN; ++j) {
            a0 = fmaf(h[j], Wc2[j * 3 + 0], a0);
            a1 = fmaf(h[j], Wc2[j * 3 + 1], a1);
            a2 = fmaf(h[j], Wc2[j * 3 + 2], a2);
        }
        c0 = 1.0f / (1.0f + __expf(-a0));
        c1 = 1.0f / (1.0f + __expf(-a1));
        c2 = 1.0f / (1.0f + __expf(-a2));
    }
    out[ray * 3 + 0] = c0;
    out[ray * 3 + 1] = c1;
    out[ray * 3 + 2] = c2;
}

extern "C" void kernel_launch(void* const* d_in, const int* in_sizes, int n_in,
                              void* d_out, int out_size, void* d_ws, size_t ws_size,
                              hipStream_t stream) {
    const float* origins    = (const float*)d_in[0];
    const float* directions = (const float*)d_in[1];
    const float* W1  = (const float*)d_in[2];
    const float* b1  = (const float*)d_in[3];
    const float* W2  = (const float*)d_in[4];
    const float* b2  = (const float*)d_in[5];
    const float* W3  = (const float*)d_in[6];
    const float* b3  = (const float*)d_in[7];
    const float* Wc1 = (const float*)d_in[8];
    const float* bc1 = (const float*)d_in[9];
    const float* Wc2 = (const float*)d_in[10];
    const float* bc2 = (const float*)d_in[11];
    float* out = (float*)d_out;

    float* W2T = (float*)d_ws;   // 128*128*4 = 64 KB

    w2_transpose_kernel<<<HIDDEN * HIDDEN / 256, 256, 0, stream>>>(W2, W2T);

    sphere_trace_kernel<<<N_RAYS / 64, 64, 0, stream>>>(
        origins, directions, W1, b1, W2T, b2, W3, b3,
        Wc1, bc1, Wc2, bc2, out);
}

// Round 2
// 1485.047 us; speedup vs baseline: 1.5960x; 1.5960x over previous
//
#include <hip/hip_runtime.h>

#define HIDDEN 128
#define HALF 64
#define N_RAYS 65536
#define NEAR_D 0.01f
#define FAR_D 10.0f
#define MAX_ITERS 32
#define HSTRIDE 132   // 128 + 4-float pad: conflict-free ds_read_b128 across lanes

// Transpose W2 [k][j] -> W2T [j][k] so per-output-row weights are contiguous
// (merged s_load scalar loads in the main kernel).
__global__ void w2_transpose_kernel(const float* __restrict__ W2,
                                    float* __restrict__ W2T) {
    int idx = blockIdx.x * blockDim.x + threadIdx.x;   // 0..16383
    int j = idx >> 7;
    int k = idx & 127;
    W2T[j * HIDDEN + k] = W2[k * HIDDEN + j];
}

// Block = 128 threads = 2 waves covering 64 rays.
// Wave w owns hidden slice [w*64, w*64+64) and layer-2 output slice [w*64, w*64+64).
// Partner half of the activations is exchanged through LDS each iteration.
__launch_bounds__(128, 2)
__global__ void sphere_trace_kernel(
    const float* __restrict__ origins,
    const float* __restrict__ directions,
    const float* __restrict__ W1,   // [3][128]
    const float* __restrict__ b1,   // [128]
    const float* __restrict__ W2T,  // [128][128] transposed: W2T[j][k] = W2[k][j]
    const float* __restrict__ b2,   // [128]
    const float* __restrict__ W3,   // [128]
    const float* __restrict__ b3,   // [1]
    const float* __restrict__ Wc1,  // [3][128]
    const float* __restrict__ bc1,  // [128]
    const float* __restrict__ Wc2,  // [128][3]
    const float* __restrict__ bc2,  // [3]
    float* __restrict__ out)        // [N][3]
{
    __shared__ float hbuf[64 * HSTRIDE];   // [ray][128+pad] activations
    __shared__ float part[2][64];          // layer-3 partial sums
    __shared__ float cpart[2][64][3];      // color partial sums

    const int lane = threadIdx.x & 63;
    // Force wave-uniformity so all derived weight addresses take the s_load path.
    const int w = __builtin_amdgcn_readfirstlane(threadIdx.x >> 6);
    const int wbase = w * HALF;            // this wave's hidden/output slice base
    const int otherbase = HALF - wbase;    // partner slice base (64 or 0)
    const int ray = blockIdx.x * 64 + lane;

    float px = origins[ray * 3 + 0];
    float py = origins[ray * 3 + 1];
    float pz = origins[ray * 3 + 2];
    const float dx = directions[ray * 3 + 0];
    const float dy = directions[ray * 3 + 1];
    const float dz = directions[ray * 3 + 2];

    float dist = 0.0f;
    bool frozen = false;

    const float* __restrict__ w1w = W1 + wbase;
    const float* __restrict__ b1w = b1 + wbase;
    const float* __restrict__ b2w = b2 + wbase;
    const float* __restrict__ w3w = W3 + wbase;
    const float b3v = b3[0];

    float4 ho[16];   // own 64 activations, constant-indexed only

    #pragma unroll 1
    for (int it = 0; it < MAX_ITERS; ++it) {
        // ---- layer 1 (own slice): ho = relu(p @ W1 + b1)
        #pragma unroll
        for (int g = 0; g < 16; ++g) {
            const int j0 = 4 * g;
            float4 v;
            v.x = fmaxf(fmaf(px, w1w[j0 + 0], fmaf(py, w1w[HIDDEN + j0 + 0],
                        fmaf(pz, w1w[2 * HIDDEN + j0 + 0], b1w[j0 + 0]))), 0.0f);
            v.y = fmaxf(fmaf(px, w1w[j0 + 1], fmaf(py, w1w[HIDDEN + j0 + 1],
                        fmaf(pz, w1w[2 * HIDDEN + j0 + 1], b1w[j0 + 1]))), 0.0f);
            v.z = fmaxf(fmaf(px, w1w[j0 + 2], fmaf(py, w1w[HIDDEN + j0 + 2],
                        fmaf(pz, w1w[2 * HIDDEN + j0 + 2], b1w[j0 + 2]))), 0.0f);
            v.w = fmaxf(fmaf(px, w1w[j0 + 3], fmaf(py, w1w[HIDDEN + j0 + 3],
                        fmaf(pz, w1w[2 * HIDDEN + j0 + 3], b1w[j0 + 3]))), 0.0f);
            ho[g] = v;
        }

        // ---- publish own half to LDS
        #pragma unroll
        for (int g = 0; g < 16; ++g)
            *(float4*)&hbuf[lane * HSTRIDE + wbase + 4 * g] = ho[g];
        __syncthreads();   // B1

        // ---- layer 2 + 3 (own output slice), 8 outputs per block
        float ps = 0.0f;
        #pragma unroll 1
        for (int jb = 0; jb < HALF; jb += 8) {
            const float* __restrict__ wr = W2T + (wbase + jb) * HIDDEN;
            float acc[8];
            #pragma unroll
            for (int o = 0; o < 8; ++o) acc[o] = b2w[jb + o];

            // partner half from LDS
            #pragma unroll
            for (int k4 = 0; k4 < 16; ++k4) {
                const float4 hv =
                    *(const float4*)&hbuf[lane * HSTRIDE + otherbase + 4 * k4];
                #pragma unroll
                for (int o = 0; o < 8; ++o) {
                    const float* __restrict__ wo =
                        wr + o * HIDDEN + otherbase + 4 * k4;
                    acc[o] = fmaf(hv.x, wo[0], acc[o]);
                    acc[o] = fmaf(hv.y, wo[1], acc[o]);
                    acc[o] = fmaf(hv.z, wo[2], acc[o]);
                    acc[o] = fmaf(hv.w, wo[3], acc[o]);
                }
            }
            // own half from registers
            #pragma unroll
            for (int k4 = 0; k4 < 16; ++k4) {
                const float4 hv = ho[k4];
                #pragma unroll
                for (int o = 0; o < 8; ++o) {
                    const float* __restrict__ wo =
                        wr + o * HIDDEN + wbase + 4 * k4;
                    acc[o] = fmaf(hv.x, wo[0], acc[o]);
                    acc[o] = fmaf(hv.y, wo[1], acc[o]);
                    acc[o] = fmaf(hv.z, wo[2], acc[o]);
                    acc[o] = fmaf(hv.w, wo[3], acc[o]);
                }
            }
            #pragma unroll
            for (int o = 0; o < 8; ++o)
                ps = fmaf(fmaxf(acc[o], 0.0f), w3w[jb + o], ps);
        }

        // ---- combine layer-3 partials
        part[w][lane] = ps;
        __syncthreads();   // B2
        const float s = part[0][lane] + part[1][lane] + b3v;

        // ---- march update (exact reference semantics; both waves identical)
        const bool valid = (s <= NEAR_D) && (dist < FAR_D);
        if (!frozen) {
            if (valid) {
                frozen = true;
            } else {
                dist += s;
                px = fmaf(dx, s, px);
                py = fmaf(dy, s, py);
                pz = fmaf(dz, s, pz);
            }
        }
        // Both waves see identical per-lane state -> identical ballot -> uniform break.
        if (__ballot(!frozen) == 0) break;
    }

    const bool mask = frozen || (dist < FAR_D);

    // ---- color MLP, split the same way: own 64 hidden units, 3 partial outputs
    const float* __restrict__ wc1w = Wc1 + wbase;
    const float* __restrict__ bc1w = bc1 + wbase;
    const float* __restrict__ wc2w = Wc2 + wbase * 3;

    float a0 = 0.0f, a1 = 0.0f, a2 = 0.0f;
    #pragma unroll
    for (int g = 0; g < 16; ++g) {
        const int j0 = 4 * g;
        #pragma unroll
        for (int q = 0; q < 4; ++q) {
            const int j = j0 + q;
            const float hc = fmaxf(fmaf(px, wc1w[j], fmaf(py, wc1w[HIDDEN + j],
                             fmaf(pz, wc1w[2 * HIDDEN + j], bc1w[j]))), 0.0f);
            a0 = fmaf(hc, wc2w[j * 3 + 0], a0);
            a1 = fmaf(hc, wc2w[j * 3 + 1], a1);
            a2 = fmaf(hc, wc2w[j * 3 + 2], a2);
        }
    }
    cpart[w][lane][0] = a0;
    cpart[w][lane][1] = a1;
    cpart[w][lane][2] = a2;
    __syncthreads();

    if (w == 0) {
        float c0 = 0.0f, c1 = 0.0f, c2 = 0.0f;
        if (mask) {
            const float t0 = a0 + cpart[1][lane][0] + bc2[0];
            const float t1 = a1 + cpart[1][lane][1] + bc2[1];
            const float t2 = a2 + cpart[1][lane][2] + bc2[2];
            c0 = 1.0f / (1.0f + __expf(-t0));
            c1 = 1.0f / (1.0f + __expf(-t1));
            c2 = 1.0f / (1.0f + __expf(-t2));
        }
        out[ray * 3 + 0] = c0;
        out[ray * 3 + 1] = c1;
        out[ray * 3 + 2] = c2;
    }
}

extern "C" void kernel_launch(void* const* d_in, const int* in_sizes, int n_in,
                              void* d_out, int out_size, void* d_ws, size_t ws_size,
                              hipStream_t stream) {
    const float* origins    = (const float*)d_in[0];
    const float* directions = (const float*)d_in[1];
    const float* W1  = (const float*)d_in[2];
    const float* b1  = (const float*)d_in[3];
    const float* W2  = (const float*)d_in[4];
    const float* b2  = (const float*)d_in[5];
    const float* W3  = (const float*)d_in[6];
    const float* b3  = (const float*)d_in[7];
    const float* Wc1 = (const float*)d_in[8];
    const float* bc1 = (const float*)d_in[9];
    const float* Wc2 = (const float*)d_in[10];
    const float* bc2 = (const float*)d_in[11];
    float* out = (float*)d_out;

    float* W2T = (float*)d_ws;   // 128*128*4 = 64 KB scratch

    w2_transpose_kernel<<<HIDDEN * HIDDEN / 256, 256, 0, stream>>>(W2, W2T);

    sphere_trace_kernel<<<N_RAYS / 64, 128, 0, stream>>>(
        origins, directions, W1, b1, W2T, b2, W3, b3,
        Wc1, bc1, Wc2, bc2, out);
}